// Round 14
// baseline (247.576 us; speedup 1.0000x reference)
//
#include <hip/hip_runtime.h>
#include <hip/hip_fp16.h>
#include <math.h>

#define NN 50000
#define EE 800000
#define FIN 128
#define FHID 64
#define FOUT 40

#define BSH  6                         // bucket = dst >> 6  (64 nodes/bucket)
#define NBKT ((NN + 63) >> 6)          // 782
#define CAP  1600                      // bucket capacity (mean 1024, sigma 32)
#define KBBLK 128                      // k_bucket blocks
#define CHK  (EE / KBBLK)              // 6250 edges per bucket-block

// ---------------- edge-dtype probe + bucket-cursor init (merged) ----------------

__global__ void k_detect(const unsigned int* __restrict__ w, int* __restrict__ flag,
                         int* __restrict__ gcur) {
    int t = threadIdx.x;                        // one block, 1024 threads
    if (t < NBKT) gcur[t] = t * CAP;            // bucket cursors
    if (t == 0) *flag = 1;                      // assume int64
    __syncthreads();
    unsigned v = w[2 * t + 1];                  // hi word if int64
    unsigned long long b = __ballot(v != 0);
    if (b && (t & 63) == 0) atomicAnd(flag, 0); // nonzero hi word -> int32
}

// ---------------- bucketed CSR build ----------------

__global__ __launch_bounds__(256) void k_bucket(const unsigned int* __restrict__ w,
                                                const int* __restrict__ flag,
                                                int* __restrict__ gcur,
                                                unsigned int* __restrict__ BKT) {
    __shared__ int hist[NBKT], rsv[NBKT], lcur[NBKT];
    const int tid = threadIdx.x;
    for (int i = tid; i < NBKT; i += 256) { hist[i] = 0; lcur[i] = 0; }
    __syncthreads();
    const bool f64 = (*flag) != 0;
    const int e0 = blockIdx.x * CHK, e1 = e0 + CHK;   // EE divisible by KBBLK

    for (int e = e0 + tid; e < e1; e += 256) {
        unsigned d = f64 ? w[2 * (EE + e)] : w[EE + e];
        atomicAdd(&hist[d >> BSH], 1);
    }
    __syncthreads();
    for (int i = tid; i < NBKT; i += 256) {
        int h = hist[i];
        rsv[i] = h ? atomicAdd(&gcur[i], h) : 0;
    }
    __syncthreads();
    for (int e = e0 + tid; e < e1; e += 256) {
        unsigned s, d;
        if (f64) { s = w[2 * e]; d = w[2 * (EE + e)]; }
        else     { s = w[e];     d = w[EE + e]; }
        unsigned b = d >> BSH;
        int idx = atomicAdd(&lcur[b], 1);
        BKT[rsv[b] + idx] = (d << 16) | s;            // both ids < 65536
    }
}

// One block per bucket: own CSR base via prefix over bucket counts, LDS stage,
// 64-node histogram -> deg -> dinv, local scan -> offsets, u16 scatter.
__global__ __launch_bounds__(256) void k_fine(const unsigned int* __restrict__ BKT,
                                              const int* __restrict__ gcur,
                                              int* __restrict__ off,
                                              float* __restrict__ dinv,
                                              unsigned short* __restrict__ ebuf) {
    __shared__ unsigned st[CAP];
    __shared__ int h[64], sc[64], lc[64];
    __shared__ int red[4];
    const int tid  = threadIdx.x;
    const int lane = tid & 63;
    const int wid  = tid >> 6;
    const int b    = blockIdx.x;

    int partial = 0;                    // base = sum_{i<b} (gcur[i] - i*CAP)
    for (int i = tid; i < b; i += 256) partial += gcur[i] - i * CAP;
#pragma unroll
    for (int o = 1; o < 64; o <<= 1) partial += __shfl_xor(partial, o, 64);
    if (lane == 0) red[wid] = partial;
    if (tid < 64) { h[tid] = 0; lc[tid] = 0; }
    __syncthreads();
    const int bb = red[0] + red[1] + red[2] + red[3];

    int cnt = gcur[b] - b * CAP;
    if (cnt > CAP) cnt = CAP;           // defensive
    for (int i = tid; i < cnt; i += 256) {
        unsigned p = BKT[b * CAP + i];
        st[i] = p;
        atomicAdd(&h[(p >> 16) & 63], 1);
    }
    __syncthreads();
    if (tid < 64) {                     // wave 0: exclusive scan of 64 degs
        int v = h[tid];
        int incl = v;
#pragma unroll
        for (int o = 1; o < 64; o <<= 1) {
            int u = __shfl_up(incl, o, 64);
            if (tid >= o) incl += u;
        }
        sc[tid] = incl - v;
        int n = (b << BSH) + tid;
        if (n < NN) {
            off[n]  = bb + sc[tid];
            dinv[n] = 1.0f / sqrtf((float)(v + 1));  // +1 self-loop
        }
    }
    if (b == 0 && tid == 64) off[NN] = EE;
    __syncthreads();
    for (int i = tid; i < cnt; i += 256) {
        unsigned p = st[i];
        int l = (p >> 16) & 63;
        int idx = atomicAdd(&lc[l], 1);
        ebuf[bb + sc[l] + idx] = (unsigned short)(p & 0xffffu);
    }
}

// ---------------- layer 1 projection: Ph[r] = fp16((X[r].W) * dinv[r]) -------

__global__ __launch_bounds__(256) void k_gemm1(const float* __restrict__ X,
                                               const float* __restrict__ W,
                                               const float* __restrict__ dinv,
                                               unsigned short* __restrict__ Ph) {
    constexpr int K = FIN, ROWS = 16, XP = K + 4;
    __shared__ float Ws[K * 64];
    __shared__ float Xs[ROWS * XP];
    const int tid  = threadIdx.x;
    const int row0 = blockIdx.x * ROWS;
    const int row_end = (NN - row0 < ROWS) ? (NN - row0) : ROWS;

    for (int i = tid; i < K * 16; i += 256)
        ((float4*)Ws)[i] = ((const float4*)W)[i];
    for (int i = tid; i < row_end * (K / 4); i += 256) {
        int r = i / (K / 4), c = i % (K / 4);
        float4 v = ((const float4*)X)[(size_t)(row0 + r) * (K / 4) + c];
        *(float4*)&Xs[r * XP + 4 * c] = v;
    }
    __syncthreads();

    const int r  = tid >> 4;
    const int cg = tid & 15;
    const int grow = row0 + r;
    if (r >= row_end) return;

    float a0 = 0.f, a1 = 0.f, a2 = 0.f, a3 = 0.f;
#pragma unroll 4
    for (int k = 0; k < K; k++) {
        float xv = Xs[r * XP + k];
        float4 wv = *(const float4*)&Ws[k * 64 + cg * 4];
        a0 = fmaf(xv, wv.x, a0);
        a1 = fmaf(xv, wv.y, a1);
        a2 = fmaf(xv, wv.z, a2);
        a3 = fmaf(xv, wv.w, a3);
    }
    float dv = dinv[grow];
    ushort4 o;
    o.x = __half_as_ushort(__float2half_rn(a0 * dv));
    o.y = __half_as_ushort(__float2half_rn(a1 * dv));
    o.z = __half_as_ushort(__float2half_rn(a2 * dv));
    o.w = __half_as_ushort(__float2half_rn(a3 * dv));
    *(ushort4*)&Ph[(size_t)grow * 64 + cg * 4] = o;
}

// ---------------- 8-wide quad-gather over fp16 rows ----------------
// Lane q=lane&7 holds cols 8q..8q+7 (uint4 = 8 halves = 16B); group g=lane>>3
// handles edge slot. 8 rows per VMEM instr; 16 edges per iteration via 2 gathers.
// f32 accumulate in 2x float4; shfl_xor(8/16/32) reduce.

__device__ __forceinline__ void acc_h8(float4& A, float4& B, uint4 u) {
    __half2 h01 = *reinterpret_cast<const __half2*>(&u.x);
    __half2 h23 = *reinterpret_cast<const __half2*>(&u.y);
    __half2 h45 = *reinterpret_cast<const __half2*>(&u.z);
    __half2 h67 = *reinterpret_cast<const __half2*>(&u.w);
    A.x += __low2float(h01); A.y += __high2float(h01);
    A.z += __low2float(h23); A.w += __high2float(h23);
    B.x += __low2float(h45); B.y += __high2float(h45);
    B.z += __low2float(h67); B.w += __high2float(h67);
}

__device__ __forceinline__ void gather_row_sum8(const uint4* __restrict__ Pu,
                                                const unsigned short* __restrict__ ebuf,
                                                int node, int s, int e, int g, int q,
                                                float4& A, float4& B) {
    A = {0.f, 0.f, 0.f, 0.f};
    B = {0.f, 0.f, 0.f, 0.f};
    if (g == 0) acc_h8(A, B, Pu[(size_t)node * 8 + q]);   // self-loop once
    int i = s;
    for (; i + 15 < e; i += 16) {          // 16 edges in flight, 2 VMEM gathers
        int c0 = ebuf[i + g], c1 = ebuf[i + g + 8];
        uint4 u0 = Pu[(size_t)c0 * 8 + q];
        uint4 u1 = Pu[(size_t)c1 * 8 + q];
        acc_h8(A, B, u0); acc_h8(A, B, u1);
    }
    if (i < e) {                           // ragged tail: clamped + masked
        int j0 = i + g, j1 = i + g + 8;
        uint4 u0 = Pu[(size_t)ebuf[j0 < e ? j0 : e - 1] * 8 + q];
        uint4 u1 = Pu[(size_t)ebuf[j1 < e ? j1 : e - 1] * 8 + q];
        if (j0 < e) acc_h8(A, B, u0);
        if (j1 < e) acc_h8(A, B, u1);
    }
#pragma unroll
    for (int o = 8; o <= 32; o <<= 1) {    // reduce 8 group partials
        A.x += __shfl_xor(A.x, o, 64); A.y += __shfl_xor(A.y, o, 64);
        A.z += __shfl_xor(A.z, o, 64); A.w += __shfl_xor(A.w, o, 64);
        B.x += __shfl_xor(B.x, o, 64); B.y += __shfl_xor(B.y, o, 64);
        B.z += __shfl_xor(B.z, o, 64); B.w += __shfl_xor(B.w, o, 64);
    }
}

__device__ __forceinline__ uint4 pack8(float4 A, float4 B) {
    uint4 o;
    o.x = (unsigned)__half_as_ushort(__float2half_rn(A.x)) |
          ((unsigned)__half_as_ushort(__float2half_rn(A.y)) << 16);
    o.y = (unsigned)__half_as_ushort(__float2half_rn(A.z)) |
          ((unsigned)__half_as_ushort(__float2half_rn(A.w)) << 16);
    o.z = (unsigned)__half_as_ushort(__float2half_rn(B.x)) |
          ((unsigned)__half_as_ushort(__float2half_rn(B.y)) << 16);
    o.w = (unsigned)__half_as_ushort(__float2half_rn(B.z)) |
          ((unsigned)__half_as_ushort(__float2half_rn(B.w)) << 16);
    return o;
}

// ---------------- layer 1 aggregation: HA = fp16(dinv * relu(agg*dinv + b)) ----

__global__ __launch_bounds__(256) void k_agg1(const uint4* __restrict__ Pu,
                                              const int* __restrict__ off,
                                              const unsigned short* __restrict__ ebuf,
                                              const float* __restrict__ dinv,
                                              const float* __restrict__ bias,
                                              uint4* __restrict__ HA) {
    const int gid  = blockIdx.x * blockDim.x + threadIdx.x;
    const int node = gid >> 6;
    const int lane = threadIdx.x & 63;
    if (node >= NN) return;
    const int g = lane >> 3, q = lane & 7;
    float4 A, B;
    gather_row_sum8(Pu, ebuf, node, off[node], off[node + 1], g, q, A, B);
    if (lane < 8) {
        float dv = dinv[node];
        const float4 b0 = *(const float4*)&bias[q * 8];
        const float4 b1 = *(const float4*)&bias[q * 8 + 4];
        float4 VA, VB;
        VA.x = fmaxf(fmaf(A.x, dv, b0.x), 0.f) * dv;
        VA.y = fmaxf(fmaf(A.y, dv, b0.y), 0.f) * dv;
        VA.z = fmaxf(fmaf(A.z, dv, b0.z), 0.f) * dv;
        VA.w = fmaxf(fmaf(A.w, dv, b0.w), 0.f) * dv;
        VB.x = fmaxf(fmaf(B.x, dv, b1.x), 0.f) * dv;
        VB.y = fmaxf(fmaf(B.y, dv, b1.y), 0.f) * dv;
        VB.z = fmaxf(fmaf(B.z, dv, b1.z), 0.f) * dv;
        VB.w = fmaxf(fmaf(B.w, dv, b1.w), 0.f) * dv;
        HA[(size_t)node * 8 + q] = pack8(VA, VB);
    }
}

// ---------------- fused agg-then-project (layers 2,3) ----------------
// 1024 threads = 16 waves, one node per wave; W staged once per 16 nodes.
// Input rows pre-scaled by dinv_src. out = (dinv_node * agg) . W + b.

template <int MOUT, bool OUTF16>
__global__ __launch_bounds__(1024) void k_fuse(const uint4* __restrict__ Hu,
                                               const float* __restrict__ W,
                                               const int* __restrict__ off,
                                               const unsigned short* __restrict__ ebuf,
                                               const float* __restrict__ dinv,
                                               const float* __restrict__ bias,
                                               void* __restrict__ outv) {
    __shared__ float Ws[64 * MOUT];
    __shared__ float aggL[16 * 64];
    const int tid  = threadIdx.x;
    const int lane = tid & 63;
    const int wv   = tid >> 6;
    const int g = lane >> 3, q = lane & 7;

    for (int i = tid; i < 64 * MOUT / 4; i += 1024)
        ((float4*)Ws)[i] = ((const float4*)W)[i];
    __syncthreads();

    const int node = blockIdx.x * 16 + wv;       // 3125*16 == NN exactly
    float4 A, B;
    gather_row_sum8(Hu, ebuf, node, off[node], off[node + 1], g, q, A, B);
    const float dv = dinv[node];
    if (lane < 8) {
        float4 t0, t1;
        t0.x = A.x * dv; t0.y = A.y * dv; t0.z = A.z * dv; t0.w = A.w * dv;
        t1.x = B.x * dv; t1.y = B.y * dv; t1.z = B.z * dv; t1.w = B.w * dv;
        *(float4*)&aggL[wv * 64 + q * 8]     = t0;
        *(float4*)&aggL[wv * 64 + q * 8 + 4] = t1;
    }
    // wave-synchronous: LDS written by lanes 0-7 of this wave, read below
    if (lane < MOUT) {
        float o = 0.f;
#pragma unroll 8
        for (int k = 0; k < 64; k++)
            o = fmaf(aggL[wv * 64 + k], Ws[k * MOUT + lane], o);
        float v = o + bias[lane];
        if constexpr (OUTF16) {
            v = fmaxf(v, 0.f);
            ((unsigned short*)outv)[(size_t)node * 64 + lane] =
                __half_as_ushort(__float2half_rn(v * dv));
        } else {
            ((float*)outv)[(size_t)node * MOUT + lane] = v;
        }
    }
}

// ---------------- launch ----------------

static inline size_t alignup(size_t x) { return (x + 255) & ~(size_t)255; }

extern "C" void kernel_launch(void* const* d_in, const int* in_sizes, int n_in,
                              void* d_out, int out_size, void* d_ws, size_t ws_size,
                              hipStream_t stream) {
    const float*        x  = (const float*)d_in[0];
    const unsigned int* ew = (const unsigned int*)d_in[1];
    const float*        W1 = (const float*)d_in[2];
    const float*        b1 = (const float*)d_in[3];
    const float*        W2 = (const float*)d_in[4];
    const float*        b2 = (const float*)d_in[5];
    const float*        W3 = (const float*)d_in[6];
    const float*        b3 = (const float*)d_in[7];

    char* w = (char*)d_ws;
    int*            flag = (int*)w;            w += alignup(4);
    int*            gcur = (int*)w;            w += alignup(NBKT * 4);
    int*            off  = (int*)w;            w += alignup((NN + 1) * 4);
    float*          dinv = (float*)w;          w += alignup(NN * 4);
    unsigned int*   BKT  = (unsigned int*)w;   w += alignup((size_t)NBKT * CAP * 4);
    unsigned short* ebuf = (unsigned short*)w; w += alignup(EE * 2);
    unsigned short* Ph   = (unsigned short*)w; w += alignup((size_t)NN * 64 * 2);
    unsigned short* HA   = (unsigned short*)w; w += alignup((size_t)NN * 64 * 2);
    unsigned short* HB   = (unsigned short*)w; w += alignup((size_t)NN * 64 * 2);

    const int BA = (NN * 64) / 256;        // 12500 (agg1: 4 node-waves/block)
    const int BG = (NN + 15) / 16;         // 3125  (gemm1 / fuse: 16 nodes/block)

    // --- edge dtype probe + bucketed CSR build (reused by all 3 layers) ---
    k_detect<<<1, 1024, 0, stream>>>(ew, flag, gcur);
    k_bucket<<<KBBLK, 256, 0, stream>>>(ew, flag, gcur, BKT);
    k_fine<<<NBKT, 256, 0, stream>>>(BKT, gcur, off, dinv, ebuf);

    // --- layer 1: project-first (128 -> 64), HA = dinv*relu(...) fp16 ---
    k_gemm1<<<BG, 256, 0, stream>>>(x, W1, dinv, Ph);
    k_agg1<<<BA, 256, 0, stream>>>((const uint4*)Ph, off, ebuf, dinv, b1,
                                   (uint4*)HA);

    // --- layer 2: fused agg-then-project (64 -> 64), HB pre-scaled fp16 ---
    k_fuse<FHID, true><<<BG, 1024, 0, stream>>>((const uint4*)HA, W2, off, ebuf,
                                                dinv, b2, HB);

    // --- layer 3: fused agg-then-project (64 -> 40), f32 out ---
    k_fuse<FOUT, false><<<BG, 1024, 0, stream>>>((const uint4*)HB, W3, off, ebuf,
                                                 dinv, b3, d_out);
}